// Round 2
// baseline (337.823 us; speedup 1.0000x reference)
//
#include <hip/hip_runtime.h>
#include <hip/hip_bf16.h>

// Problem constants: B=2, S=2048, D=1024, H=16, A=64
#define B_ 2
#define S_ 2048
#define D_ 1024
#define H_ 16
#define A_ 64

typedef __attribute__((ext_vector_type(8))) short bf16x8;
typedef __attribute__((ext_vector_type(4))) float f32x4;

__device__ inline short f2bf(float f) {
    union { float f; unsigned u; } x; x.f = f;
    unsigned r = x.u + 0x7fff + ((x.u >> 16) & 1);   // RNE
    return (short)(r >> 16);
}

// ---------------- kernel 1: fp32 -> bf16 cast of residual ----------------
__global__ __launch_bounds__(256) void cast_kernel(const float* __restrict__ x,
                                                   short* __restrict__ y, int n) {
    int i = (blockIdx.x * 256 + threadIdx.x) * 8;
    if (i < n) {
        float4 a = *(const float4*)(x + i);
        float4 b = *(const float4*)(x + i + 4);
        bf16x8 o;
        o[0]=f2bf(a.x); o[1]=f2bf(a.y); o[2]=f2bf(a.z); o[3]=f2bf(a.w);
        o[4]=f2bf(b.x); o[5]=f2bf(b.y); o[6]=f2bf(b.z); o[7]=f2bf(b.w);
        *(bf16x8*)(y + i) = o;
    }
}

// ---------------- kernel 2: QKV projection ----------------
// grid (32 s-tiles, 16 heads, 3 qkv). Out tile 128 s x 64 a.
// Q/K stored [B,H,S,A] bf16; V stored transposed [B,H,A,S] bf16.
__global__ __launch_bounds__(256) void qkv_kernel(
    const short* __restrict__ X,                       // [B*S, D] bf16
    const float* __restrict__ Wq, const float* __restrict__ Wk, const float* __restrict__ Wv,
    const float* __restrict__ bq, const float* __restrict__ bk, const float* __restrict__ bv,
    short* __restrict__ Qb, short* __restrict__ Kb, short* __restrict__ Vt) {
    const int stile = blockIdx.x, h = blockIdx.y, sel = blockIdx.z;
    const float* W    = sel == 0 ? Wq : (sel == 1 ? Wk : Wv);
    const float* bias = sel == 0 ? bq : (sel == 1 ? bk : bv);
    __shared__ short Xl[128 * 40];   // pad 32 -> 40 (80B row stride: 2-way bank alias = free)
    __shared__ short Wl[64 * 40];    // W tile transposed: [a][k]
    const int tid = threadIdx.x, wv = tid >> 6, lane = tid & 63, quad = lane >> 4, l16 = lane & 15;
    f32x4 acc[2][4] = {};
    const int bs0 = stile * 128;
    for (int k0 = 0; k0 < D_; k0 += 32) {
        // stage X tile [128][32]: 128*32 = 4096 shorts = 256 thr * 2 * 8
        #pragma unroll
        for (int r2 = 0; r2 < 2; r2++) {
            int row = (tid >> 2) + r2 * 64, c8 = (tid & 3) * 8;
            *(bf16x8*)&Xl[row * 40 + c8] = *(const bf16x8*)&X[(bs0 + row) * D_ + k0 + c8];
        }
        // stage W tile [32 k][64 a] transposed into Wl[a][k]: 2048 floats = 256 thr * 8
        {
            int kr = tid >> 3, a0 = (tid & 7) * 8;
            const float* src = &W[(h * D_ + k0 + kr) * A_ + a0];
            float4 f0 = *(const float4*)src, f1 = *(const float4*)(src + 4);
            float v[8] = {f0.x, f0.y, f0.z, f0.w, f1.x, f1.y, f1.z, f1.w};
            #pragma unroll
            for (int j = 0; j < 8; j++) Wl[(a0 + j) * 40 + kr] = f2bf(v[j]);
        }
        __syncthreads();
        #pragma unroll
        for (int rt = 0; rt < 2; rt++) {
            bf16x8 a = *(bf16x8*)&Xl[(wv * 32 + rt * 16 + l16) * 40 + quad * 8];
            #pragma unroll
            for (int ct = 0; ct < 4; ct++) {
                bf16x8 b = *(bf16x8*)&Wl[(ct * 16 + l16) * 40 + quad * 8];
                acc[rt][ct] = __builtin_amdgcn_mfma_f32_16x16x32_bf16(a, b, acc[rt][ct], 0, 0, 0);
            }
        }
        __syncthreads();
    }
    const int b = bs0 >> 11, s0 = bs0 & (S_ - 1);
    const int bh = b * H_ + h;
    if (sel < 2) {
        short* dst = sel == 0 ? Qb : Kb;
        const float scale = sel == 0 ? 0.125f : 1.0f;   // 1/sqrt(64), exact in bf16
        #pragma unroll
        for (int rt = 0; rt < 2; rt++)
            #pragma unroll
            for (int ct = 0; ct < 4; ct++) {
                int a = ct * 16 + l16;
                float bi = bias[h * A_ + a];
                #pragma unroll
                for (int r = 0; r < 4; r++) {
                    int s = s0 + wv * 32 + rt * 16 + quad * 4 + r;
                    dst[(bh * S_ + s) * A_ + a] = f2bf((acc[rt][ct][r] + bi) * scale);
                }
            }
    } else {
        #pragma unroll
        for (int rt = 0; rt < 2; rt++)
            #pragma unroll
            for (int ct = 0; ct < 4; ct++) {
                int a = ct * 16 + l16;
                float bi = bias[h * A_ + a];
                short4 pk;
                pk.x = f2bf(acc[rt][ct][0] + bi);
                pk.y = f2bf(acc[rt][ct][1] + bi);
                pk.z = f2bf(acc[rt][ct][2] + bi);
                pk.w = f2bf(acc[rt][ct][3] + bi);
                int s = s0 + wv * 32 + rt * 16 + quad * 4;   // multiple of 4 -> 8B aligned
                *(short4*)&Vt[(bh * A_ + a) * S_ + s] = pk;
            }
    }
}

// ---------------- kernel 3: flash attention (causal, online softmax) ----------------
// grid (32 q-tiles, 16 heads, 2 batch). Block 256 = 4 waves; wave owns 16 q-rows.
__global__ __launch_bounds__(256) void flash_kernel(
    const short* __restrict__ Qb, const short* __restrict__ Kb,
    const short* __restrict__ Vt, short* __restrict__ Z) {
    const int qt = blockIdx.x, h = blockIdx.y, b = blockIdx.z;
    const int bh = b * H_ + h;
    __shared__ short Ql[64 * 72], Kl[64 * 72], Vl[64 * 72], Pl[4 * 16 * 72];
    const int tid = threadIdx.x, wv = tid >> 6, lane = tid & 63, quad = lane >> 4, l16 = lane & 15;
    // tile staging geometry: 64x64 tile = 4096 shorts = 256 thr * 16 shorts (two bf16x8)
    const int srow = tid >> 2, sc0 = (tid & 3) * 16;
    {   // load Q tile once (already scaled by 1/8 in qkv_kernel)
        const short* src = &Qb[(bh * S_ + qt * 64 + srow) * A_ + sc0];
        *(bf16x8*)&Ql[srow * 72 + sc0]     = *(const bf16x8*)src;
        *(bf16x8*)&Ql[srow * 72 + sc0 + 8] = *(const bf16x8*)(src + 8);
    }
    f32x4 O[4] = {};
    float m_i[4], l_i[4];
    #pragma unroll
    for (int r = 0; r < 4; r++) { m_i[r] = -1e30f; l_i[r] = 0.f; }
    __syncthreads();
    for (int kt = 0; kt <= qt; ++kt) {
        {   // stage K [t][a] and Vt [a][t], full 64x64 each
            const short* ksrc = &Kb[(bh * S_ + kt * 64 + srow) * A_ + sc0];
            *(bf16x8*)&Kl[srow * 72 + sc0]     = *(const bf16x8*)ksrc;
            *(bf16x8*)&Kl[srow * 72 + sc0 + 8] = *(const bf16x8*)(ksrc + 8);
            const short* vsrc = &Vt[(bh * A_ + srow) * S_ + kt * 64 + sc0];
            *(bf16x8*)&Vl[srow * 72 + sc0]     = *(const bf16x8*)vsrc;
            *(bf16x8*)&Vl[srow * 72 + sc0 + 8] = *(const bf16x8*)(vsrc + 8);
        }
        __syncthreads();
        // S = Q K^T (wave rows wv*16.., all 64 cols)
        f32x4 sacc[4];
        #pragma unroll
        for (int ct = 0; ct < 4; ct++) {
            f32x4 acc = {};
            #pragma unroll
            for (int kk = 0; kk < 2; kk++) {
                bf16x8 a  = *(bf16x8*)&Ql[(wv * 16 + l16) * 72 + kk * 32 + quad * 8];
                bf16x8 bb = *(bf16x8*)&Kl[(ct * 16 + l16) * 72 + kk * 32 + quad * 8];
                acc = __builtin_amdgcn_mfma_f32_16x16x32_bf16(a, bb, acc, 0, 0, 0);
            }
            sacc[ct] = acc;
        }
        if (kt == qt) {   // causal mask on diagonal tile (-1e30 == ref's -1e5 after exp underflow)
            #pragma unroll
            for (int ct = 0; ct < 4; ct++) {
                int col = kt * 64 + ct * 16 + l16;
                #pragma unroll
                for (int r = 0; r < 4; r++) {
                    int row = qt * 64 + wv * 16 + quad * 4 + r;
                    if (col > row) sacc[ct][r] = -1e30f;
                }
            }
        }
        // online softmax, rows live in (quad, reg); reduce across the 16 lanes l16
        #pragma unroll
        for (int r = 0; r < 4; r++) {
            float v = fmaxf(fmaxf(sacc[0][r], sacc[1][r]), fmaxf(sacc[2][r], sacc[3][r]));
            #pragma unroll
            for (int mm = 1; mm < 16; mm <<= 1) v = fmaxf(v, __shfl_xor(v, mm));
            float mn = fmaxf(m_i[r], v);
            float alpha = __expf(m_i[r] - mn);
            float rs = 0.f;
            #pragma unroll
            for (int ct = 0; ct < 4; ct++) {
                float p = __expf(sacc[ct][r] - mn);
                sacc[ct][r] = p; rs += p;
            }
            #pragma unroll
            for (int mm = 1; mm < 16; mm <<= 1) rs += __shfl_xor(rs, mm);
            l_i[r] = l_i[r] * alpha + rs;
            m_i[r] = mn;
            #pragma unroll
            for (int ct = 0; ct < 4; ct++) O[ct][r] *= alpha;
        }
        // P: C-layout -> A-layout via wave-private LDS (DS ops are in-order per wave)
        short* Pw = &Pl[wv * 16 * 72];
        #pragma unroll
        for (int ct = 0; ct < 4; ct++)
            #pragma unroll
            for (int r = 0; r < 4; r++)
                Pw[(quad * 4 + r) * 72 + ct * 16 + l16] = f2bf(sacc[ct][r]);
        __builtin_amdgcn_s_waitcnt(0xC07F);   // lgkmcnt(0) only — cross-lane LDS dep within wave
        // O += P V
        #pragma unroll
        for (int ct = 0; ct < 4; ct++) {
            #pragma unroll
            for (int kk = 0; kk < 2; kk++) {
                bf16x8 a  = *(bf16x8*)&Pw[l16 * 72 + kk * 32 + quad * 8];
                bf16x8 bb = *(bf16x8*)&Vl[(ct * 16 + l16) * 72 + kk * 32 + quad * 8];
                O[ct] = __builtin_amdgcn_mfma_f32_16x16x32_bf16(a, bb, O[ct], 0, 0, 0);
            }
        }
        __syncthreads();
    }
    // epilogue: Z[b, s, h*64+a] bf16
    #pragma unroll
    for (int ct = 0; ct < 4; ct++) {
        int a = ct * 16 + l16;
        #pragma unroll
        for (int r = 0; r < 4; r++) {
            int s = qt * 64 + wv * 16 + quad * 4 + r;
            Z[(b * S_ + s) * (H_ * A_) + h * A_ + a] = f2bf(O[ct][r] / l_i[r]);
        }
    }
}

// ---------------- kernel 4: output projection ----------------
// out[bs, d] = sum_ha Z[bs, ha] * Wo[ha, d] + bo[d]
__global__ __launch_bounds__(256) void proj_kernel(
    const short* __restrict__ Z, const float* __restrict__ Wo,
    const float* __restrict__ bo, float* __restrict__ out) {
    const int mt = blockIdx.x, nt = blockIdx.y;
    __shared__ short Zl[128 * 40], Wl[64 * 40];
    const int tid = threadIdx.x, wv = tid >> 6, lane = tid & 63, quad = lane >> 4, l16 = lane & 15;
    f32x4 acc[2][4] = {};
    const int n0 = nt * 64;
    for (int k0 = 0; k0 < H_ * A_; k0 += 32) {
        #pragma unroll
        for (int r2 = 0; r2 < 2; r2++) {
            int row = (tid >> 2) + r2 * 64, c8 = (tid & 3) * 8;
            *(bf16x8*)&Zl[row * 40 + c8] = *(const bf16x8*)&Z[(mt * 128 + row) * (H_ * A_) + k0 + c8];
        }
        {
            int kr = tid >> 3, a0 = (tid & 7) * 8;
            const float* src = &Wo[(k0 + kr) * D_ + n0 + a0];
            float4 f0 = *(const float4*)src, f1 = *(const float4*)(src + 4);
            float v[8] = {f0.x, f0.y, f0.z, f0.w, f1.x, f1.y, f1.z, f1.w};
            #pragma unroll
            for (int j = 0; j < 8; j++) Wl[(a0 + j) * 40 + kr] = f2bf(v[j]);
        }
        __syncthreads();
        #pragma unroll
        for (int rt = 0; rt < 2; rt++) {
            bf16x8 a = *(bf16x8*)&Zl[(wv * 32 + rt * 16 + l16) * 40 + quad * 8];
            #pragma unroll
            for (int ct = 0; ct < 4; ct++) {
                bf16x8 bb = *(bf16x8*)&Wl[(ct * 16 + l16) * 40 + quad * 8];
                acc[rt][ct] = __builtin_amdgcn_mfma_f32_16x16x32_bf16(a, bb, acc[rt][ct], 0, 0, 0);
            }
        }
        __syncthreads();
    }
    #pragma unroll
    for (int rt = 0; rt < 2; rt++)
        #pragma unroll
        for (int ct = 0; ct < 4; ct++) {
            int d = n0 + ct * 16 + l16;
            float bi = bo[d];
            #pragma unroll
            for (int r = 0; r < 4; r++) {
                int row = mt * 128 + wv * 32 + rt * 16 + quad * 4 + r;
                out[row * D_ + d] = acc[rt][ct][r] + bi;
            }
        }
}

extern "C" void kernel_launch(void* const* d_in, const int* in_sizes, int n_in,
                              void* d_out, int out_size, void* d_ws, size_t ws_size,
                              hipStream_t stream) {
    const float* residual = (const float*)d_in[0];
    const float* Wq = (const float*)d_in[1];
    const float* Wk = (const float*)d_in[2];
    const float* Wv = (const float*)d_in[3];
    const float* Wo = (const float*)d_in[4];
    const float* bq = (const float*)d_in[5];
    const float* bk = (const float*)d_in[6];
    const float* bv = (const float*)d_in[7];
    const float* bo = (const float*)d_in[8];
    float* out = (float*)d_out;

    char* ws = (char*)d_ws;
    const size_t NE = (size_t)B_ * S_ * D_;          // 4,194,304 elements
    short* Xbf = (short*)(ws);                       //  8 MB
    short* Qb  = (short*)(ws + 8ull  * 1024 * 1024); //  8 MB  [B,H,S,A]
    short* Kb  = (short*)(ws + 16ull * 1024 * 1024); //  8 MB  [B,H,S,A]
    short* Vt  = (short*)(ws + 24ull * 1024 * 1024); //  8 MB  [B,H,A,S]
    short* Zb  = (short*)(ws + 32ull * 1024 * 1024); //  8 MB  [B,S,H*A]

    hipLaunchKernelGGL(cast_kernel, dim3((int)(NE / (256 * 8))), dim3(256), 0, stream,
                       residual, Xbf, (int)NE);
    hipLaunchKernelGGL(qkv_kernel, dim3(B_ * S_ / 128, H_, 3), dim3(256), 0, stream,
                       Xbf, Wq, Wk, Wv, bq, bk, bv, Qb, Kb, Vt);
    hipLaunchKernelGGL(flash_kernel, dim3(S_ / 64, H_, B_), dim3(256), 0, stream,
                       Qb, Kb, Vt, Zb);
    hipLaunchKernelGGL(proj_kernel, dim3(B_ * S_ / 128, D_ / 64), dim3(256), 0, stream,
                       Zb, Wo, bo, out);
}

// Round 3
// 222.855 us; speedup vs baseline: 1.5159x; 1.5159x over previous
//
#include <hip/hip_runtime.h>
#include <hip/hip_bf16.h>

// Problem constants: B=2, S=2048, D=1024, H=16, A=64
#define B_ 2
#define S_ 2048
#define D_ 1024
#define H_ 16
#define A_ 64

typedef __attribute__((ext_vector_type(8))) short bf16x8;
typedef __attribute__((ext_vector_type(4))) float f32x4;

#define QSCALE 0.1803368801111204f   // 1/sqrt(64) * log2(e): softmax done in exp2 domain

__device__ inline short f2bf(float f) {
    union { float f; unsigned u; } x; x.f = f;
    unsigned r = x.u + 0x7fff + ((x.u >> 16) & 1);   // RNE
    return (short)(r >> 16);
}

// ---------------- kernel 1: fp32 -> bf16 cast of residual ----------------
__global__ __launch_bounds__(256) void cast_kernel(const float* __restrict__ x,
                                                   short* __restrict__ y, int n) {
    int i = (blockIdx.x * 256 + threadIdx.x) * 8;
    if (i < n) {
        float4 a = *(const float4*)(x + i);
        float4 b = *(const float4*)(x + i + 4);
        bf16x8 o;
        o[0]=f2bf(a.x); o[1]=f2bf(a.y); o[2]=f2bf(a.z); o[3]=f2bf(a.w);
        o[4]=f2bf(b.x); o[5]=f2bf(b.y); o[6]=f2bf(b.z); o[7]=f2bf(b.w);
        *(bf16x8*)(y + i) = o;
    }
}

// ---------------- kernel 1b: transpose+cast weights to bf16 [n][k] ----------------
// z<3: Wq/Wk/Wv head yy, k-tile kt -> Wt rows n = z*1024 + yy*64 + a, cols k
// z==3: Wo ([k=h*64+a][n=d]) n-tile yy, k-tile kt -> Wot rows n=d, cols k
__global__ __launch_bounds__(256) void wtrans_kernel(
    const float* __restrict__ Wq, const float* __restrict__ Wk,
    const float* __restrict__ Wv, const float* __restrict__ Wo,
    short* __restrict__ Wt, short* __restrict__ Wot) {
    const int kt = blockIdx.x, yy = blockIdx.y, z = blockIdx.z;
    __shared__ short T[64 * 72];
    const int tid = threadIdx.x;
    const int r = tid >> 2, c0 = (tid & 3) * 16;
    const float* src;
    if (z < 3) {
        const float* W = z == 0 ? Wq : (z == 1 ? Wk : Wv);
        src = &W[yy * (D_ * A_) + (kt * 64 + r) * A_ + c0];
    } else {
        src = &Wo[(kt * 64 + r) * D_ + yy * 64 + c0];
    }
    #pragma unroll
    for (int q = 0; q < 4; q++) {
        float4 f = *(const float4*)(src + q * 4);
        T[r * 72 + c0 + q * 4 + 0] = f2bf(f.x);
        T[r * 72 + c0 + q * 4 + 1] = f2bf(f.y);
        T[r * 72 + c0 + q * 4 + 2] = f2bf(f.z);
        T[r * 72 + c0 + q * 4 + 3] = f2bf(f.w);
    }
    __syncthreads();
    const int a = tid >> 2, kc = (tid & 3) * 16;
    bf16x8 o0, o1;
    #pragma unroll
    for (int j = 0; j < 8; j++) {
        o0[j] = T[(kc + j) * 72 + a];
        o1[j] = T[(kc + 8 + j) * 72 + a];
    }
    const int n_base = (z < 3) ? z * 1024 + yy * 64 : yy * 64;
    short* dst = (z < 3) ? &Wt[(n_base + a) * D_ + kt * 64 + kc]
                         : &Wot[(n_base + a) * D_ + kt * 64 + kc];
    *(bf16x8*)dst = o0;
    *(bf16x8*)(dst + 8) = o1;
}

// ---------------- kernel 2: QKV as one GEMM [4096 x 3072 x 1024] ----------------
// grid (32 Mtiles, 24 Ntiles); tile 128x128, BK=32, double-buffered + reg prefetch.
// col n: sel = n>>10, h = (n>>6)&15, a = n&63. Q scaled by QSCALE; V written transposed.
__global__ __launch_bounds__(256) void qkv_gemm(
    const short* __restrict__ X, const short* __restrict__ Wt,
    const float* __restrict__ bq, const float* __restrict__ bk, const float* __restrict__ bv,
    short* __restrict__ Qb, short* __restrict__ Kb, short* __restrict__ Vt) {
    const int mt = blockIdx.x, nt = blockIdx.y;
    const int m0 = mt * 128, n0 = nt * 128;
    const int sel = n0 >> 10;
    __shared__ short Xl[2][128 * 40], Wl[2][128 * 40];
    const int tid = threadIdx.x, wv = tid >> 6, lane = tid & 63, quad = lane >> 4, l16 = lane & 15;
    const int grow = tid >> 1, gk = (tid & 1) * 16;
    f32x4 acc[4][4] = {};
    bf16x8 xr0, xr1, wr0, wr1;
    {
        const short* xs = &X[(m0 + grow) * D_ + gk];
        xr0 = *(const bf16x8*)xs; xr1 = *(const bf16x8*)(xs + 8);
        const short* wsp = &Wt[(n0 + grow) * D_ + gk];
        wr0 = *(const bf16x8*)wsp; wr1 = *(const bf16x8*)(wsp + 8);
    }
    const int rm = (wv & 1) * 64, cn = (wv >> 1) * 64;
    for (int i = 0; i < 32; i++) {
        const int bu = i & 1;
        *(bf16x8*)&Xl[bu][grow * 40 + gk]     = xr0;
        *(bf16x8*)&Xl[bu][grow * 40 + gk + 8] = xr1;
        *(bf16x8*)&Wl[bu][grow * 40 + gk]     = wr0;
        *(bf16x8*)&Wl[bu][grow * 40 + gk + 8] = wr1;
        __syncthreads();
        if (i < 31) {
            const int k0 = (i + 1) * 32;
            const short* xs = &X[(m0 + grow) * D_ + k0 + gk];
            xr0 = *(const bf16x8*)xs; xr1 = *(const bf16x8*)(xs + 8);
            const short* wsp = &Wt[(n0 + grow) * D_ + k0 + gk];
            wr0 = *(const bf16x8*)wsp; wr1 = *(const bf16x8*)(wsp + 8);
        }
        bf16x8 af[4];
        #pragma unroll
        for (int rt = 0; rt < 4; rt++)
            af[rt] = *(bf16x8*)&Xl[bu][(rm + rt * 16 + l16) * 40 + quad * 8];
        #pragma unroll
        for (int ct = 0; ct < 4; ct++) {
            bf16x8 bf = *(bf16x8*)&Wl[bu][(cn + ct * 16 + l16) * 40 + quad * 8];
            #pragma unroll
            for (int rt = 0; rt < 4; rt++)
                acc[rt][ct] = __builtin_amdgcn_mfma_f32_16x16x32_bf16(af[rt], bf, acc[rt][ct], 0, 0, 0);
        }
        // no trailing barrier: next iteration writes the other LDS buffer
    }
    const int b = m0 >> 11;
    const float* bias = sel == 0 ? bq : (sel == 1 ? bk : bv);
    if (sel < 2) {
        short* dst = sel == 0 ? Qb : Kb;
        const float scale = sel == 0 ? QSCALE : 1.0f;
        #pragma unroll
        for (int ct = 0; ct < 4; ct++) {
            const int n = n0 + cn + ct * 16 + l16;
            const int h = (n >> 6) & 15, a = n & 63;
            const float bi = bias[n & 1023];
            #pragma unroll
            for (int rt = 0; rt < 4; rt++)
                #pragma unroll
                for (int r = 0; r < 4; r++) {
                    const int row = m0 + rm + rt * 16 + quad * 4 + r;
                    const int s = row & (S_ - 1);
                    dst[(((b * H_) + h) * S_ + s) * A_ + a] = f2bf((acc[rt][ct][r] + bi) * scale);
                }
        }
    } else {
        #pragma unroll
        for (int ct = 0; ct < 4; ct++) {
            const int n = n0 + cn + ct * 16 + l16;
            const int h = (n >> 6) & 15, a = n & 63;
            const float bi = bias[n & 1023];
            #pragma unroll
            for (int rt = 0; rt < 4; rt++) {
                short4 pk;
                pk.x = f2bf(acc[rt][ct][0] + bi);
                pk.y = f2bf(acc[rt][ct][1] + bi);
                pk.z = f2bf(acc[rt][ct][2] + bi);
                pk.w = f2bf(acc[rt][ct][3] + bi);
                const int row = m0 + rm + rt * 16 + quad * 4;
                const int s = row & (S_ - 1);
                *(short4*)&Vt[(((b * H_) + h) * A_ + a) * S_ + s] = pk;
            }
        }
    }
}

// ---------------- kernel 3: flash attention, paired q-tiles, double-buffered K/V ----------------
// grid (16 pairs, 16 heads, 2 batch). Block = 4 waves; wave owns 16 q-rows of each tile.
// Pair p handles q-tiles qlo=p and qhi=31-p: exactly 33 tile-updates per block (balanced),
// K/V staged once per kt and shared by both q-tiles.
__global__ __launch_bounds__(256) void flash_kernel(
    const short* __restrict__ Qb, const short* __restrict__ Kb,
    const short* __restrict__ Vt, short* __restrict__ Z) {
    const int p = blockIdx.x, h = blockIdx.y, b = blockIdx.z;
    const int bh = b * H_ + h;
    const int qlo = p, qhi = 31 - p;
    __shared__ short Ql[2][64 * 72], Kl[2][64 * 72], Vl[2][64 * 72], Pl[4][16 * 72];
    const int tid = threadIdx.x, wv = tid >> 6, lane = tid & 63, quad = lane >> 4, l16 = lane & 15;
    const int srow = tid >> 2, sc0 = (tid & 3) * 16;
    // stage both Q tiles (Q pre-scaled by QSCALE in qkv_gemm)
    #pragma unroll
    for (int t = 0; t < 2; t++) {
        const int qt = t ? qhi : qlo;
        const short* src = &Qb[(bh * S_ + qt * 64 + srow) * A_ + sc0];
        *(bf16x8*)&Ql[t][srow * 72 + sc0]     = *(const bf16x8*)src;
        *(bf16x8*)&Ql[t][srow * 72 + sc0 + 8] = *(const bf16x8*)(src + 8);
    }
    f32x4 O[2][4] = {};
    float m_i[2][4], l_i[2][4];
    #pragma unroll
    for (int t = 0; t < 2; t++)
        #pragma unroll
        for (int r = 0; r < 4; r++) { m_i[t][r] = -1e30f; l_i[t][r] = 0.f; }
    // preload kt=0
    bf16x8 kr0, kr1, vr0, vr1;
    {
        const short* ks = &Kb[(bh * S_ + srow) * A_ + sc0];
        kr0 = *(const bf16x8*)ks; kr1 = *(const bf16x8*)(ks + 8);
        const short* vs = &Vt[(bh * A_ + srow) * S_ + sc0];
        vr0 = *(const bf16x8*)vs; vr1 = *(const bf16x8*)(vs + 8);
    }
    for (int kt = 0; kt <= qhi; kt++) {
        const int bu = kt & 1;
        *(bf16x8*)&Kl[bu][srow * 72 + sc0]     = kr0;
        *(bf16x8*)&Kl[bu][srow * 72 + sc0 + 8] = kr1;
        *(bf16x8*)&Vl[bu][srow * 72 + sc0]     = vr0;
        *(bf16x8*)&Vl[bu][srow * 72 + sc0 + 8] = vr1;
        __syncthreads();
        if (kt < qhi) {   // prefetch kt+1 while computing kt
            const short* ks = &Kb[(bh * S_ + (kt + 1) * 64 + srow) * A_ + sc0];
            kr0 = *(const bf16x8*)ks; kr1 = *(const bf16x8*)(ks + 8);
            const short* vs = &Vt[(bh * A_ + srow) * S_ + (kt + 1) * 64 + sc0];
            vr0 = *(const bf16x8*)vs; vr1 = *(const bf16x8*)(vs + 8);
        }
        const int nt_upd = (kt <= qlo) ? 2 : 1;
        for (int u = 0; u < nt_upd; u++) {
            const int t = (u == 0) ? 1 : 0;          // qhi first, then qlo
            const int qt = t ? qhi : qlo;
            f32x4 sacc[4];
            #pragma unroll
            for (int ct = 0; ct < 4; ct++) {
                f32x4 acc = {};
                #pragma unroll
                for (int kk = 0; kk < 2; kk++) {
                    bf16x8 a  = *(bf16x8*)&Ql[t][(wv * 16 + l16) * 72 + kk * 32 + quad * 8];
                    bf16x8 bb = *(bf16x8*)&Kl[bu][(ct * 16 + l16) * 72 + kk * 32 + quad * 8];
                    acc = __builtin_amdgcn_mfma_f32_16x16x32_bf16(a, bb, acc, 0, 0, 0);
                }
                sacc[ct] = acc;
            }
            if (kt == qt) {   // diagonal tile: causal mask (scores in log2 domain)
                #pragma unroll
                for (int ct = 0; ct < 4; ct++) {
                    const int cl = ct * 16 + l16;
                    #pragma unroll
                    for (int r = 0; r < 4; r++) {
                        const int rl = wv * 16 + quad * 4 + r;
                        if (cl > rl) sacc[ct][r] = -1e30f;
                    }
                }
            }
            #pragma unroll
            for (int r = 0; r < 4; r++) {
                float v = fmaxf(fmaxf(sacc[0][r], sacc[1][r]), fmaxf(sacc[2][r], sacc[3][r]));
                #pragma unroll
                for (int mm = 1; mm < 16; mm <<= 1) v = fmaxf(v, __shfl_xor(v, mm));
                const float mn = fmaxf(m_i[t][r], v);
                const float alpha = exp2f(m_i[t][r] - mn);
                float rs = 0.f;
                #pragma unroll
                for (int ct = 0; ct < 4; ct++) {
                    const float pe = exp2f(sacc[ct][r] - mn);
                    sacc[ct][r] = pe; rs += pe;
                }
                l_i[t][r] = l_i[t][r] * alpha + rs;   // per-lane partial; reduced in epilogue
                m_i[t][r] = mn;
                #pragma unroll
                for (int ct = 0; ct < 4; ct++) O[t][ct][r] *= alpha;
            }
            // P: C-layout -> A-layout via wave-private LDS
            short* Pw = &Pl[wv][0];
            #pragma unroll
            for (int ct = 0; ct < 4; ct++)
                #pragma unroll
                for (int r = 0; r < 4; r++)
                    Pw[(quad * 4 + r) * 72 + ct * 16 + l16] = f2bf(sacc[ct][r]);
            __builtin_amdgcn_s_waitcnt(0xC07F);   // lgkmcnt(0): cross-lane LDS dep within wave
            #pragma unroll
            for (int ct = 0; ct < 4; ct++) {
                #pragma unroll
                for (int kk = 0; kk < 2; kk++) {
                    bf16x8 a  = *(bf16x8*)&Pw[l16 * 72 + kk * 32 + quad * 8];
                    bf16x8 bb = *(bf16x8*)&Vl[bu][(ct * 16 + l16) * 72 + kk * 32 + quad * 8];
                    O[t][ct] = __builtin_amdgcn_mfma_f32_16x16x32_bf16(a, bb, O[t][ct], 0, 0, 0);
                }
            }
        }
        // no trailing barrier: next iteration stages into the other K/V buffer
    }
    // epilogue: reduce per-lane l partials, write Z[b, s, h*64+a]
    #pragma unroll
    for (int t = 0; t < 2; t++) {
        const int qt = t ? qhi : qlo;
        float lsum[4];
        #pragma unroll
        for (int r = 0; r < 4; r++) {
            float rs = l_i[t][r];
            #pragma unroll
            for (int mm = 1; mm < 16; mm <<= 1) rs += __shfl_xor(rs, mm);
            lsum[r] = rs;
        }
        #pragma unroll
        for (int ct = 0; ct < 4; ct++) {
            const int a = ct * 16 + l16;
            #pragma unroll
            for (int r = 0; r < 4; r++) {
                const int s = qt * 64 + wv * 16 + quad * 4 + r;
                Z[(b * S_ + s) * (H_ * A_) + h * A_ + a] = f2bf(O[t][ct][r] / lsum[r]);
            }
        }
    }
}

// ---------------- kernel 4: output projection GEMM [4096 x 1024 x 1024] ----------------
__global__ __launch_bounds__(256) void proj_gemm(
    const short* __restrict__ Zb, const short* __restrict__ Wot,
    const float* __restrict__ bo, float* __restrict__ out) {
    const int mt = blockIdx.x, nt = blockIdx.y;
    const int m0 = mt * 128, n0 = nt * 128;
    __shared__ short Xl[2][128 * 40], Wl[2][128 * 40];
    const int tid = threadIdx.x, wv = tid >> 6, lane = tid & 63, quad = lane >> 4, l16 = lane & 15;
    const int grow = tid >> 1, gk = (tid & 1) * 16;
    f32x4 acc[4][4] = {};
    bf16x8 xr0, xr1, wr0, wr1;
    {
        const short* xs = &Zb[(m0 + grow) * D_ + gk];
        xr0 = *(const bf16x8*)xs; xr1 = *(const bf16x8*)(xs + 8);
        const short* wsp = &Wot[(n0 + grow) * D_ + gk];
        wr0 = *(const bf16x8*)wsp; wr1 = *(const bf16x8*)(wsp + 8);
    }
    const int rm = (wv & 1) * 64, cn = (wv >> 1) * 64;
    for (int i = 0; i < 32; i++) {
        const int bu = i & 1;
        *(bf16x8*)&Xl[bu][grow * 40 + gk]     = xr0;
        *(bf16x8*)&Xl[bu][grow * 40 + gk + 8] = xr1;
        *(bf16x8*)&Wl[bu][grow * 40 + gk]     = wr0;
        *(bf16x8*)&Wl[bu][grow * 40 + gk + 8] = wr1;
        __syncthreads();
        if (i < 31) {
            const int k0 = (i + 1) * 32;
            const short* xs = &Zb[(m0 + grow) * D_ + k0 + gk];
            xr0 = *(const bf16x8*)xs; xr1 = *(const bf16x8*)(xs + 8);
            const short* wsp = &Wot[(n0 + grow) * D_ + k0 + gk];
            wr0 = *(const bf16x8*)wsp; wr1 = *(const bf16x8*)(wsp + 8);
        }
        bf16x8 af[4];
        #pragma unroll
        for (int rt = 0; rt < 4; rt++)
            af[rt] = *(bf16x8*)&Xl[bu][(rm + rt * 16 + l16) * 40 + quad * 8];
        #pragma unroll
        for (int ct = 0; ct < 4; ct++) {
            bf16x8 bf = *(bf16x8*)&Wl[bu][(cn + ct * 16 + l16) * 40 + quad * 8];
            #pragma unroll
            for (int rt = 0; rt < 4; rt++)
                acc[rt][ct] = __builtin_amdgcn_mfma_f32_16x16x32_bf16(af[rt], bf, acc[rt][ct], 0, 0, 0);
        }
    }
    #pragma unroll
    for (int ct = 0; ct < 4; ct++) {
        const int n = n0 + cn + ct * 16 + l16;
        const float bi = bo[n];
        #pragma unroll
        for (int rt = 0; rt < 4; rt++)
            #pragma unroll
            for (int r = 0; r < 4; r++) {
                const int row = m0 + rm + rt * 16 + quad * 4 + r;
                out[row * D_ + n] = acc[rt][ct][r] + bi;
            }
    }
}

extern "C" void kernel_launch(void* const* d_in, const int* in_sizes, int n_in,
                              void* d_out, int out_size, void* d_ws, size_t ws_size,
                              hipStream_t stream) {
    const float* residual = (const float*)d_in[0];
    const float* Wq = (const float*)d_in[1];
    const float* Wk = (const float*)d_in[2];
    const float* Wv = (const float*)d_in[3];
    const float* Wo = (const float*)d_in[4];
    const float* bq = (const float*)d_in[5];
    const float* bk = (const float*)d_in[6];
    const float* bv = (const float*)d_in[7];
    const float* bo = (const float*)d_in[8];
    float* out = (float*)d_out;

    char* ws = (char*)d_ws;
    const size_t NE = (size_t)B_ * S_ * D_;           // 4,194,304
    short* Xbf = (short*)(ws);                        //  8 MB  [B*S, D] bf16
    short* Wt  = (short*)(ws +  8ull * 1024 * 1024);  //  6 MB  [3072, 1024] bf16 (qkv, transposed)
    short* Wot = (short*)(ws + 14ull * 1024 * 1024);  //  2 MB  [1024, 1024] bf16 (Wo, transposed)
    short* Qb  = (short*)(ws + 16ull * 1024 * 1024);  //  8 MB  [B,H,S,A]
    short* Kb  = (short*)(ws + 24ull * 1024 * 1024);  //  8 MB  [B,H,S,A]
    short* Vt  = (short*)(ws + 32ull * 1024 * 1024);  //  8 MB  [B,H,A,S]
    short* Zb  = (short*)(ws + 40ull * 1024 * 1024);  //  8 MB  [B,S,H*A]

    hipLaunchKernelGGL(cast_kernel, dim3((int)(NE / (256 * 8))), dim3(256), 0, stream,
                       residual, Xbf, (int)NE);
    hipLaunchKernelGGL(wtrans_kernel, dim3(16, 16, 4), dim3(256), 0, stream,
                       Wq, Wk, Wv, Wo, Wt, Wot);
    hipLaunchKernelGGL(qkv_gemm, dim3(32, 24), dim3(256), 0, stream,
                       Xbf, Wt, bq, bk, bv, Qb, Kb, Vt);
    hipLaunchKernelGGL(flash_kernel, dim3(16, H_, B_), dim3(256), 0, stream,
                       Qb, Kb, Vt, Zb);
    hipLaunchKernelGGL(proj_gemm, dim3(32, 8), dim3(256), 0, stream,
                       Zb, Wot, bo, out);
}